// Round 4
// baseline (738.807 us; speedup 1.0000x reference)
//
#include <hip/hip_runtime.h>
#include <hip/hip_bf16.h>

// Problem constants (fixed by reference)
constexpr int NN   = 50000;   // nodes
constexpr int NE   = 800000;  // edges per relation
constexpr int NR   = 3;       // relations
constexpr int DIN  = 96;
constexpr int DH   = 96;
constexpr int DOUT = 64;
constexpr int SLOT = 64;      // max in-degree slots (Poisson(16): P(>64) ~ 1e-22)
constexpr int NP   = 3;       // feature passes, 32 dims (64B bf16) each

// ---- bf16 helpers (RNE) ----------------------------------------------------
__device__ __forceinline__ unsigned short f2b(float f) {
    unsigned int u = __float_as_uint(f);
    u += 0x7fffu + ((u >> 16) & 1u);       // round-to-nearest-even
    return (unsigned short)(u >> 16);
}
__device__ __forceinline__ float blo(unsigned int u) { return __uint_as_float(u << 16); }
__device__ __forceinline__ float bhi(unsigned int u) { return __uint_as_float(u & 0xffff0000u); }
__device__ __forceinline__ unsigned int pack2(float lo, float hi) {
    return (unsigned int)f2b(lo) | ((unsigned int)f2b(hi) << 16);
}

// ---------------------------------------------------------------------------
// One-pass CSR build: bin src ids into fixed-size per-(relation,dst) slots.
// ---------------------------------------------------------------------------
__global__ void bin_kernel(const int* __restrict__ src,
                           const int* __restrict__ dst,
                           int* __restrict__ deg,              // [NR*NN]
                           unsigned short* __restrict__ slots) // [NR*NN][SLOT]
{
    int gid = blockIdx.x * 256 + threadIdx.x;
    if (gid >= NR * NE) return;
    int r = gid / NE;                       // compile-time divisor
    int d = dst[gid];
    int s = src[gid];
    int pos = atomicAdd(&deg[r * NN + d], 1);
    if (pos < SLOT)
        __builtin_nontemporal_store((unsigned short)s,
            &slots[((size_t)(r * NN + d)) * SLOT + pos]);
}

// ---------------------------------------------------------------------------
// x [NN][96] f32 -> pass-major bf16 tables xp[NP][NN][16 dwords]
// thread i handles 8 consecutive f32 (chunk q of node n).
// ---------------------------------------------------------------------------
__global__ void xform_kernel(const float* __restrict__ in,
                             unsigned int* __restrict__ outp)
{
    int i = blockIdx.x * 256 + threadIdx.x;
    if (i >= NN * 12) return;
    int n = i / 12, q = i - n * 12;         // q: 0..11 (8 dims each)
    int p = q >> 2, c = q & 3;              // pass, chunk-in-pass
    const float* s = in + (size_t)n * 96 + q * 8;
    float4 a = *reinterpret_cast<const float4*>(s);
    float4 b = *reinterpret_cast<const float4*>(s + 4);
    uint4 o;
    o.x = pack2(a.x, a.y);
    o.y = pack2(a.z, a.w);
    o.z = pack2(b.x, b.y);
    o.w = pack2(b.z, b.w);
    *reinterpret_cast<uint4*>(outp + ((size_t)p * NN + n) * 16 + c * 4) = o;
}

// ---------------------------------------------------------------------------
// Aggregate one 32-dim pass for ALL relations. 16 lanes per (relation,node):
// lane t reads dword t of each gathered 64B row (one cache line per row).
// Table Tp is 3.2 MB -> L2-resident. Slot indices read nontemporally.
// ---------------------------------------------------------------------------
__global__ __launch_bounds__(256)
void agg_pass_kernel(const unsigned int* __restrict__ Tp,      // [NN][16]
                     const unsigned short* __restrict__ slots, // [NR*NN][SLOT]
                     const int* __restrict__ deg,              // [NR*NN]
                     unsigned int* __restrict__ agg,           // [NR][NP][NN][16]
                     int p)
{
    int gid = blockIdx.x * 256 + threadIdx.x;
    int grp = gid >> 4, t = gid & 15;
    if (grp >= NR * NN) return;
    int r = grp / NN, n = grp - r * NN;
    const unsigned short* sl = slots + (size_t)grp * SLOT;
    int e = deg[grp];
    if (e > SLOT) e = SLOT;

    float a0 = 0.f, a1 = 0.f;
    int i = 0;
    for (; i + 7 < e; i += 8) {             // 8 independent row loads in flight
        int s0 = __builtin_nontemporal_load(sl + i + 0);
        int s1 = __builtin_nontemporal_load(sl + i + 1);
        int s2 = __builtin_nontemporal_load(sl + i + 2);
        int s3 = __builtin_nontemporal_load(sl + i + 3);
        int s4 = __builtin_nontemporal_load(sl + i + 4);
        int s5 = __builtin_nontemporal_load(sl + i + 5);
        int s6 = __builtin_nontemporal_load(sl + i + 6);
        int s7 = __builtin_nontemporal_load(sl + i + 7);
        unsigned int u0 = Tp[(size_t)s0 * 16 + t];
        unsigned int u1 = Tp[(size_t)s1 * 16 + t];
        unsigned int u2 = Tp[(size_t)s2 * 16 + t];
        unsigned int u3 = Tp[(size_t)s3 * 16 + t];
        unsigned int u4 = Tp[(size_t)s4 * 16 + t];
        unsigned int u5 = Tp[(size_t)s5 * 16 + t];
        unsigned int u6 = Tp[(size_t)s6 * 16 + t];
        unsigned int u7 = Tp[(size_t)s7 * 16 + t];
        a0 += blo(u0) + blo(u1) + blo(u2) + blo(u3)
            + blo(u4) + blo(u5) + blo(u6) + blo(u7);
        a1 += bhi(u0) + bhi(u1) + bhi(u2) + bhi(u3)
            + bhi(u4) + bhi(u5) + bhi(u6) + bhi(u7);
    }
    for (; i + 1 < e; i += 2) {
        int s0 = __builtin_nontemporal_load(sl + i + 0);
        int s1 = __builtin_nontemporal_load(sl + i + 1);
        unsigned int u0 = Tp[(size_t)s0 * 16 + t];
        unsigned int u1 = Tp[(size_t)s1 * 16 + t];
        a0 += blo(u0) + blo(u1);
        a1 += bhi(u0) + bhi(u1);
    }
    if (i < e) {
        unsigned int u0 = Tp[(size_t)__builtin_nontemporal_load(sl + i) * 16 + t];
        a0 += blo(u0);
        a1 += bhi(u0);
    }
    float inv = 1.0f / (float)(e > 0 ? e : 1);
    agg[(((size_t)r * NP + p) * NN + n) * 16 + t] = pack2(a0 * inv, a1 * inv);
}

// ---------------------------------------------------------------------------
// 3-relation GEMM + bias + tanh + mean; single output write.
// Reads pass-major input Hp and pass-major agg; stages both to LDS f32.
// For layer 1 (OUT16): writes bf16 pass-major output, which may ALIAS Hp
// (each block reads only its own 16 nodes' rows, then overwrites them).
// ---------------------------------------------------------------------------
template <int NOUT, int YR, int TM, bool OUT16>
__global__ __launch_bounds__(256)
void gemm3_kernel(const unsigned int* Hp,                  // [NP][NN][16] (no restrict: may alias o16)
                  const unsigned int* __restrict__ agg,    // [NR][NP][NN][16]
                  const float* __restrict__ Ws,            // [NR][96][NOUT]
                  const float* __restrict__ Wn,            // [NR][96][NOUT]
                  const float* __restrict__ bias,          // [NR][NOUT]
                  unsigned short* o16,                     // [NP][NN][32] bf16
                  float* __restrict__ o32)                 // [NN][NOUT] f32
{
    __shared__ float xs[16][96];
    __shared__ float gs[NR][16][96];

    const int tid  = threadIdx.x;
    const int n0   = blockIdx.x * 16;
    const int node = tid >> 4;
    const int t    = tid & 15;

    #pragma unroll
    for (int k = 0; k < NP; ++k) {
        unsigned int u = Hp[((size_t)k * NN + n0 + node) * 16 + t];
        *reinterpret_cast<float2*>(&xs[node][k * 32 + 2 * t]) =
            make_float2(blo(u), bhi(u));
    }
    #pragma unroll
    for (int k = 0; k < NR * NP; ++k) {
        int r = k / NP, p = k - r * NP;
        unsigned int u = agg[(((size_t)r * NP + p) * NN + n0 + node) * 16 + t];
        *reinterpret_cast<float2*>(&gs[r][node][p * 32 + 2 * t]) =
            make_float2(blo(u), bhi(u));
    }
    __syncthreads();

    if (tid < NOUT * YR) {
        const int tx = tid % NOUT;
        const int ty = tid / NOUT;
        const int row0 = ty * TM;

        float res[TM];
        #pragma unroll
        for (int j = 0; j < TM; ++j) res[j] = 0.f;

        for (int r = 0; r < NR; ++r) {
            const float* Wsr = Ws + (size_t)r * 96 * NOUT;
            const float* Wnr = Wn + (size_t)r * 96 * NOUT;
            float acc[TM];
            #pragma unroll
            for (int j = 0; j < TM; ++j) acc[j] = 0.f;

            for (int d4 = 0; d4 < 96; d4 += 4) {
                float xr[TM][4], gr[TM][4];
                #pragma unroll
                for (int j = 0; j < TM; ++j) {
                    float4 t1 = *reinterpret_cast<const float4*>(&xs[row0 + j][d4]);
                    float4 t2 = *reinterpret_cast<const float4*>(&gs[r][row0 + j][d4]);
                    xr[j][0] = t1.x; xr[j][1] = t1.y; xr[j][2] = t1.z; xr[j][3] = t1.w;
                    gr[j][0] = t2.x; gr[j][1] = t2.y; gr[j][2] = t2.z; gr[j][3] = t2.w;
                }
                #pragma unroll
                for (int dd = 0; dd < 4; ++dd) {
                    float wsv = Wsr[(d4 + dd) * NOUT + tx];
                    float wnv = Wnr[(d4 + dd) * NOUT + tx];
                    #pragma unroll
                    for (int j = 0; j < TM; ++j)
                        acc[j] += xr[j][dd] * wsv + gr[j][dd] * wnv;
                }
            }
            const float bb = bias[r * NOUT + tx];
            #pragma unroll
            for (int j = 0; j < TM; ++j)
                res[j] += tanhf(acc[j] + bb);
        }

        const float third = 1.0f / (float)NR;
        #pragma unroll
        for (int j = 0; j < TM; ++j) {
            const int n = n0 + row0 + j;
            float v = res[j] * third;
            if (OUT16) {
                int p = tx >> 5, c = tx & 31;
                o16[((size_t)p * NN + n) * 32 + c] = f2b(v);
            } else {
                o32[(size_t)n * NOUT + tx] = v;
            }
        }
    }
}

// ---------------------------------------------------------------------------
extern "C" void kernel_launch(void* const* d_in, const int* in_sizes, int n_in,
                              void* d_out, int out_size, void* d_ws, size_t ws_size,
                              hipStream_t stream)
{
    const float* x   = (const float*)d_in[0];
    const int*   src = (const int*)d_in[1];
    const int*   dst = (const int*)d_in[2];
    const float* Ws1 = (const float*)d_in[3];
    const float* Wn1 = (const float*)d_in[4];
    const float* b1  = (const float*)d_in[5];
    const float* Ws2 = (const float*)d_in[6];
    const float* Wn2 = (const float*)d_in[7];
    const float* b2  = (const float*)d_in[8];
    float* out = (float*)d_out;

    // Workspace layout (256B-aligned), ~58.2 MB total (round-2-proven size).
    char* ws = (char*)d_ws;
    size_t o = 0;
    auto alloc = [&](size_t bytes) {
        size_t p = o;
        o += (bytes + 255) & ~(size_t)255;
        return p;
    };
    int* deg = (int*)(ws + alloc((size_t)NR * NN * 4));                         // 0.6 MB
    unsigned short* slots = (unsigned short*)(ws + alloc((size_t)NR * NN * SLOT * 2)); // 19.2 MB
    // xp is pass-major x for layer 1; layer-1 GEMM overwrites it IN PLACE with
    // pass-major h1 (block-private rows). xform regenerates it every call.
    unsigned int* xp = (unsigned int*)(ws + alloc((size_t)NP * NN * 16 * 4));   // 9.6 MB
    unsigned int* agg = (unsigned int*)(ws + alloc((size_t)NR * NP * NN * 16 * 4)); // 28.8 MB

    // CSR build + layout transform
    hipMemsetAsync(deg, 0, (size_t)NR * NN * 4, stream);
    bin_kernel<<<(NR * NE + 255) / 256, 256, 0, stream>>>(src, dst, deg, slots);
    xform_kernel<<<(NN * 12 + 255) / 256, 256, 0, stream>>>(x, xp);

    // --- Layer 1 ---
    for (int p = 0; p < NP; ++p)
        agg_pass_kernel<<<(NR * NN * 16 + 255) / 256, 256, 0, stream>>>(
            xp + (size_t)p * NN * 16, slots, deg, agg, p);
    gemm3_kernel<DH, 2, 8, true><<<NN / 16, 256, 0, stream>>>(
        xp, agg, Ws1, Wn1, b1, (unsigned short*)xp, (float*)nullptr);

    // --- Layer 2 (xp now holds pass-major h1) ---
    for (int p = 0; p < NP; ++p)
        agg_pass_kernel<<<(NR * NN * 16 + 255) / 256, 256, 0, stream>>>(
            xp + (size_t)p * NN * 16, slots, deg, agg, p);
    gemm3_kernel<DOUT, 4, 4, false><<<NN / 16, 256, 0, stream>>>(
        xp, agg, Ws2, Wn2, b2, (unsigned short*)nullptr, out);
}

// Round 5
// 410.415 us; speedup vs baseline: 1.8001x; 1.8001x over previous
//
#include <hip/hip_runtime.h>
#include <hip/hip_bf16.h>

// Problem constants (fixed by reference)
constexpr int NN   = 50000;   // nodes
constexpr int NE   = 800000;  // edges per relation
constexpr int NR   = 3;       // relations
constexpr int DIN  = 96;
constexpr int DH   = 96;
constexpr int DOUT = 64;
constexpr int SLOT = 64;      // max in-degree slots (Poisson(16): P(>64) ~ 1e-22)

typedef __attribute__((ext_vector_type(8))) short bf16x8;  // MFMA A/B frag (4 VGPRs)
typedef __attribute__((ext_vector_type(4))) float f32x4;   // MFMA C/D frag

// ---- bf16 helpers (RNE) ----------------------------------------------------
__device__ __forceinline__ unsigned short f2b(float f) {
    unsigned int u = __float_as_uint(f);
    u += 0x7fffu + ((u >> 16) & 1u);       // round-to-nearest-even
    return (unsigned short)(u >> 16);
}
__device__ __forceinline__ float blo(unsigned int u) { return __uint_as_float(u << 16); }
__device__ __forceinline__ float bhi(unsigned int u) { return __uint_as_float(u & 0xffff0000u); }
__device__ __forceinline__ unsigned int pack2(float lo, float hi) {
    return (unsigned int)f2b(lo) | ((unsigned int)f2b(hi) << 16);
}

struct __align__(4) U3 { unsigned int x, y, z; };          // 12B row-slice gather

// ---------------------------------------------------------------------------
// One-pass CSR build: bin src ids into fixed-size per-(relation,dst) slots.
// ---------------------------------------------------------------------------
__global__ void bin_kernel(const int* __restrict__ src,
                           const int* __restrict__ dst,
                           int* __restrict__ deg,              // [NR*NN]
                           unsigned short* __restrict__ slots) // [NR*NN][SLOT]
{
    int gid = blockIdx.x * 256 + threadIdx.x;
    if (gid >= NR * NE) return;
    int r = gid / NE;                       // compile-time divisor
    int d = dst[gid];
    int s = src[gid];
    int pos = atomicAdd(&deg[r * NN + d], 1);
    if (pos < SLOT)
        __builtin_nontemporal_store((unsigned short)s,
            &slots[((size_t)(r * NN + d)) * SLOT + pos]);
}

// ---- f32 -> bf16 bulk convert (8 elems/thread) -----------------------------
__global__ void f32_to_bf16_kernel(const float* __restrict__ in,
                                   unsigned short* __restrict__ out, int n)
{
    int i = (blockIdx.x * 256 + threadIdx.x) * 8;
    if (i >= n) return;
    float4 a = *reinterpret_cast<const float4*>(in + i);
    float4 b = *reinterpret_cast<const float4*>(in + i + 4);
    uint4 o;
    o.x = pack2(a.x, a.y);
    o.y = pack2(a.z, a.w);
    o.z = pack2(b.x, b.y);
    o.w = pack2(b.z, b.w);
    *reinterpret_cast<uint4*>(out + i) = o;
}

// ---- weight transpose: W[r][k][n] f32 -> WT[r][n][k] bf16 ------------------
__global__ void wT_kernel(const float* __restrict__ in,
                          unsigned short* __restrict__ out,
                          int KD, int ND, int tot)
{
    int gid = blockIdx.x * 256 + threadIdx.x;
    if (gid >= tot) return;
    int k = gid % KD;
    int rn = gid / KD;
    int n = rn % ND;
    int r = rn / ND;
    out[gid] = f2b(in[((size_t)r * KD + k) * ND + n]);
}

// ---------------------------------------------------------------------------
// Mean-aggregation, all 3 relations, full 96 dims. 16 lanes per (rel,node);
// lane t gathers 12B (dwords 3t..3t+2) of each 192B source row (dwordx3).
// Slot indices fetched 8-at-a-time as uint4 (broadcast across the 16 lanes).
// ---------------------------------------------------------------------------
__global__ __launch_bounds__(256)
void agg_kernel(const unsigned int* __restrict__ Hb,        // [NN][48] dwords
                const unsigned short* __restrict__ slots,   // [NR*NN][SLOT]
                const int* __restrict__ deg,                // [NR*NN]
                unsigned int* __restrict__ aggb)            // [NR][NN][48]
{
    int gid = blockIdx.x * 256 + threadIdx.x;
    int grp = gid >> 4, t = gid & 15;
    if (grp >= NR * NN) return;
    const unsigned short* sl = slots + (size_t)grp * SLOT;
    int e = deg[grp];
    if (e > SLOT) e = SLOT;

    float a0 = 0.f, a1 = 0.f, a2 = 0.f, a3 = 0.f, a4 = 0.f, a5 = 0.f;
    int i = 0;
    for (; i + 8 <= e; i += 8) {
        uint4 iv = *reinterpret_cast<const uint4*>(sl + i);   // 8 u16 indices
        unsigned int idx[8] = { iv.x & 0xffffu, iv.x >> 16,
                                iv.y & 0xffffu, iv.y >> 16,
                                iv.z & 0xffffu, iv.z >> 16,
                                iv.w & 0xffffu, iv.w >> 16 };
        U3 v[8];
        #pragma unroll
        for (int q = 0; q < 8; ++q)
            v[q] = *reinterpret_cast<const U3*>(Hb + (size_t)idx[q] * 48 + 3 * t);
        #pragma unroll
        for (int q = 0; q < 8; ++q) {
            a0 += blo(v[q].x); a1 += bhi(v[q].x);
            a2 += blo(v[q].y); a3 += bhi(v[q].y);
            a4 += blo(v[q].z); a5 += bhi(v[q].z);
        }
    }
    for (; i < e; ++i) {
        unsigned int idx = sl[i];
        U3 v = *reinterpret_cast<const U3*>(Hb + (size_t)idx * 48 + 3 * t);
        a0 += blo(v.x); a1 += bhi(v.x);
        a2 += blo(v.y); a3 += bhi(v.y);
        a4 += blo(v.z); a5 += bhi(v.z);
    }
    float inv = 1.0f / (float)(e > 0 ? e : 1);
    unsigned int* o = aggb + (size_t)grp * 48 + 3 * t;   // grp = r*NN+n
    o[0] = pack2(a0 * inv, a1 * inv);
    o[1] = pack2(a2 * inv, a3 * inv);
    o[2] = pack2(a4 * inv, a5 * inv);
}

// ---------------------------------------------------------------------------
// MFMA layer: 4 waves/block, each wave owns 16 nodes and computes all NOUT
// cols for all 3 relations:  res = mean_r tanh(X@Ws_r + AGG_r@Wn_r + b_r).
// A-frags: lane l holds row (l&15), k = (l>>4)*8..+7 -> 16B contiguous loads
// from row-major bf16. B-frags from pre-transposed WT[n][k] (L2-hot).
// D-layout (m89-verified): col = lane&15, row = (lane>>4)*4 + j.
// Layer 1 writes o16 IN PLACE over Hb (each row is read only by its owner
// wave's A-frag loads, which precede its stores; clamped tail reads are
// discarded) -- saves a 9.6MB buffer.
// ---------------------------------------------------------------------------
template <int NOUT, bool OUT16>
__global__ __launch_bounds__(256)
void mfma_layer_kernel(const unsigned short* Hb,                // [NN][96] (may alias o16)
                       const unsigned short* __restrict__ aggb, // [NR][NN][96]
                       const unsigned short* __restrict__ Wts,  // [NR][NOUT][96] bf16 (Ws^T)
                       const unsigned short* __restrict__ Wtn,  // [NR][NOUT][96]
                       const float* __restrict__ bias,          // [NR][NOUT]
                       unsigned short* o16,                     // [NN][96] bf16
                       float* __restrict__ o32)                 // [NN][NOUT] f32
{
    const int w    = threadIdx.x >> 6;           // wave 0..3
    const int l    = threadIdx.x & 63;
    const int n0   = blockIdx.x * 64 + w * 16;   // wave's first node
    const int arow = l & 15, asel = l >> 4;
    int na = n0 + arow;
    if (na > NN - 1) na = NN - 1;                // clamp (stores guarded)

    bf16x8 ax[3], ag[NR][3];
    {
        const unsigned short* xr = Hb + (size_t)na * 96 + asel * 8;
        #pragma unroll
        for (int kb = 0; kb < 3; ++kb)
            ax[kb] = *reinterpret_cast<const bf16x8*>(xr + kb * 32);
        #pragma unroll
        for (int r = 0; r < NR; ++r) {
            const unsigned short* gr = aggb + ((size_t)r * NN + na) * 96 + asel * 8;
            #pragma unroll
            for (int kb = 0; kb < 3; ++kb)
                ag[r][kb] = *reinterpret_cast<const bf16x8*>(gr + kb * 32);
        }
    }

    constexpr int NC = NOUT / 16;
    #pragma unroll
    for (int c = 0; c < NC; ++c) {
        f32x4 acc[NR];
        #pragma unroll
        for (int r = 0; r < NR; ++r) acc[r] = (f32x4){0.f, 0.f, 0.f, 0.f};

        #pragma unroll
        for (int r = 0; r < NR; ++r) {
            const unsigned short* bs = Wts + ((size_t)r * NOUT + c * 16 + arow) * 96 + asel * 8;
            const unsigned short* bn = Wtn + ((size_t)r * NOUT + c * 16 + arow) * 96 + asel * 8;
            #pragma unroll
            for (int kb = 0; kb < 3; ++kb) {
                acc[r] = __builtin_amdgcn_mfma_f32_16x16x32_bf16(
                    ax[kb], *reinterpret_cast<const bf16x8*>(bs + kb * 32), acc[r], 0, 0, 0);
                acc[r] = __builtin_amdgcn_mfma_f32_16x16x32_bf16(
                    ag[r][kb], *reinterpret_cast<const bf16x8*>(bn + kb * 32), acc[r], 0, 0, 0);
            }
        }

        const int col = c * 16 + arow;
        const float b0 = bias[col];
        const float b1 = bias[NOUT + col];
        const float b2 = bias[2 * NOUT + col];
        #pragma unroll
        for (int j = 0; j < 4; ++j) {
            int node = n0 + asel * 4 + j;
            if (node < NN) {
                float v = (tanhf(acc[0][j] + b0) + tanhf(acc[1][j] + b1)
                         + tanhf(acc[2][j] + b2)) * (1.0f / 3.0f);
                if (OUT16) o16[(size_t)node * 96 + col] = f2b(v);
                else       o32[(size_t)node * DOUT + col] = v;
            }
        }
    }
}

// ---------------------------------------------------------------------------
extern "C" void kernel_launch(void* const* d_in, const int* in_sizes, int n_in,
                              void* d_out, int out_size, void* d_ws, size_t ws_size,
                              hipStream_t stream)
{
    const float* x   = (const float*)d_in[0];
    const int*   src = (const int*)d_in[1];
    const int*   dst = (const int*)d_in[2];
    const float* Ws1 = (const float*)d_in[3];
    const float* Wn1 = (const float*)d_in[4];
    const float* b1  = (const float*)d_in[5];
    const float* Ws2 = (const float*)d_in[6];
    const float* Wn2 = (const float*)d_in[7];
    const float* b2  = (const float*)d_in[8];
    float* out = (float*)d_out;

    // Workspace layout (256B-aligned), ~58.4 MB total.
    char* ws = (char*)d_ws;
    size_t o = 0;
    auto alloc = [&](size_t bytes) {
        size_t p = o;
        o += (bytes + 255) & ~(size_t)255;
        return p;
    };
    int* deg = (int*)(ws + alloc((size_t)NR * NN * 4));                          // 0.6 MB
    unsigned short* slots = (unsigned short*)(ws + alloc((size_t)NR * NN * SLOT * 2)); // 19.2 MB
    unsigned short* xb = (unsigned short*)(ws + alloc((size_t)NN * 96 * 2));     // 9.6 MB (x, then h1 in place)
    unsigned short* aggb = (unsigned short*)(ws + alloc((size_t)NR * NN * 96 * 2)); // 28.8 MB
    unsigned short* wt = (unsigned short*)(ws + alloc((size_t)(2 * NR * DIN * DH
                                                    + 2 * NR * DH * DOUT) * 2)); // 0.18 MB
    unsigned short* wt1s = wt;                         // [3][96][96]
    unsigned short* wt1n = wt1s + NR * DIN * DH;       // [3][96][96]
    unsigned short* wt2s = wt1n + NR * DIN * DH;       // [3][64][96]
    unsigned short* wt2n = wt2s + NR * DH * DOUT;      // [3][64][96]

    // CSR build + dtype/layout prep
    hipMemsetAsync(deg, 0, (size_t)NR * NN * 4, stream);
    bin_kernel<<<(NR * NE + 255) / 256, 256, 0, stream>>>(src, dst, deg, slots);
    f32_to_bf16_kernel<<<(NN * 96 / 8 + 255) / 256, 256, 0, stream>>>(x, xb, NN * 96);
    wT_kernel<<<(NR * DIN * DH + 255) / 256, 256, 0, stream>>>(Ws1, wt1s, DIN, DH, NR * DIN * DH);
    wT_kernel<<<(NR * DIN * DH + 255) / 256, 256, 0, stream>>>(Wn1, wt1n, DIN, DH, NR * DIN * DH);
    wT_kernel<<<(NR * DH * DOUT + 255) / 256, 256, 0, stream>>>(Ws2, wt2s, DH, DOUT, NR * DH * DOUT);
    wT_kernel<<<(NR * DH * DOUT + 255) / 256, 256, 0, stream>>>(Wn2, wt2n, DH, DOUT, NR * DH * DOUT);

    constexpr int AGG_GRID  = NR * NN * 16 / 256;      // 9375
    constexpr int GEMM_GRID = (NN + 63) / 64;          // 782

    // --- Layer 1: h1 (bf16, in place over xb) ---
    agg_kernel<<<AGG_GRID, 256, 0, stream>>>(
        (const unsigned int*)xb, slots, deg, (unsigned int*)aggb);
    mfma_layer_kernel<DH, true><<<GEMM_GRID, 256, 0, stream>>>(
        xb, aggb, wt1s, wt1n, b1, xb, (float*)nullptr);

    // --- Layer 2: out (f32) ---
    agg_kernel<<<AGG_GRID, 256, 0, stream>>>(
        (const unsigned int*)xb, slots, deg, (unsigned int*)aggb);
    mfma_layer_kernel<DOUT, false><<<GEMM_GRID, 256, 0, stream>>>(
        xb, aggb, wt2s, wt2n, b2, (unsigned short*)nullptr, out);
}